// Round 1
// baseline (299.843 us; speedup 1.0000x reference)
//
#include <hip/hip_runtime.h>

// NMS + farthest-pair + Voronoi masks, B=131072 heatmaps of 14x14 fp32.
// 4 batches per 64-lane wave (16 lanes = 1 DPP row per batch).
// Argmax = single u32-key max reduction (value<<8 | 255-flat): value-max and
// first-occurrence index in ONE tree+4-step-DPP reduction, pure VALU, no LDS.
// Survivors of (v > 0.6) lie in (0.6,1) -> fp32 exponent fixed at 126, so the
// 23-bit mantissa (+1) preserves exact float ordering in integer compare.
//
// This revision: VGPR diet (no va[]/xs[]/ys[]/m[]/n[] arrays -- only key[16]
// + packed xy[16]), v_max3_u32-friendly max tree, packed-byte window test
// (1 sub + 2 byte range checks), nontemporal loads/stores (touch-once
// streams; don't thrash L2/L3 against the harness's 822MB re-poison fill).

typedef float v4f __attribute__((ext_vector_type(4)));

constexpr int L = 14;
constexpr int NPIX = L * L;   // 196
constexpr int NV4 = NPIX / 4; // 49

template <int CTRL>
__device__ __forceinline__ unsigned dpp_maxu(unsigned x) {
    unsigned y = (unsigned)__builtin_amdgcn_update_dpp(0, (int)x, CTRL, 0xF, 0xF, true);
    return x > y ? x : y;
}
__device__ __forceinline__ unsigned row_max16u(unsigned x) {
    x = dpp_maxu<0xB1>(x);   // quad_perm xor1
    x = dpp_maxu<0x4E>(x);   // quad_perm xor2
    x = dpp_maxu<0x141>(x);  // row_half_mirror
    x = dpp_maxu<0x140>(x);  // row_mirror
    return x;
}
__device__ __forceinline__ unsigned umax2(unsigned a, unsigned b) { return a > b ? a : b; }
__device__ __forceinline__ unsigned umax3(unsigned a, unsigned b, unsigned c) {
    return umax2(umax2(a, b), c);  // -> v_max3_u32
}

__global__ __launch_bounds__(256) void nms_kernel(const v4f* __restrict__ hm4,
                                                  v4f* __restrict__ out4, int B) {
    const int lane = threadIdx.x & 63;
    const int s = lane & 15;
    const int b = blockIdx.x * 16 + ((threadIdx.x >> 6) << 2) + (lane >> 4);
    if (b >= B) return;

    const v4f* __restrict__ bp = hm4 + (size_t)b * NV4;
    v4f a0 = __builtin_nontemporal_load(bp + s);
    v4f a1 = __builtin_nontemporal_load(bp + 16 + s);
    v4f a2 = __builtin_nontemporal_load(bp + 32 + s);
    v4f a3 = {0.f, 0.f, 0.f, 0.f};   // sentinel slots = zero heat
    if (s == 0) a3 = __builtin_nontemporal_load(bp + 48);

    // flat(slot i) = 4s + 64*(i>>2) + (i&3); sentinel flats 196..255 have
    // inv < 60 so they lose to every real zero-slot (inv >= 60). Low byte of
    // key is ALWAYS inv, so "suppress" == key &= 255.
    unsigned key[16];
    int xy[16];                       // (x<<8)|y, x in [0,18], y in [0,13]
    const int s4 = s << 2;
#pragma unroll
    for (int i = 0; i < 16; ++i) {
        const int fl = s4 + ((i >> 2) << 6) + (i & 3);
        const int x = fl / L, y = fl - (fl / L) * L;
        xy[i] = (x << 8) | y;
        const float v = (i < 4) ? a0[i] : (i < 8) ? a1[i - 4] : (i < 12) ? a2[i - 8] : a3[i - 12];
        const unsigned inv = 255u - (unsigned)fl;
        const unsigned kpos = (((__float_as_uint(v) & 0x7FFFFFu) + 1u) << 8) | inv;
        key[i] = (v > 0.6f) ? kpos : inv;
    }

    int peaks[4];
#pragma unroll
    for (int r = 0; r < 4; ++r) {
        // balanced tree: 5x max3 over 15 + fold with key[15] (8 VALU total)
        const unsigned t0 = umax3(key[0], key[1], key[2]);
        const unsigned t1 = umax3(key[3], key[4], key[5]);
        const unsigned t2 = umax3(key[6], key[7], key[8]);
        const unsigned t3 = umax3(key[9], key[10], key[11]);
        const unsigned t4 = umax3(key[12], key[13], key[14]);
        unsigned mk = umax2(umax3(t0, t1, t2), umax3(t3, t4, key[15]));
        mk = row_max16u(mk);
        const int flat = 255 - (int)(mk & 255u);
        peaks[r] = flat;
        if (r < 3) {
            // window [ax-5, ax+5) x [ay-5, ay+5); 0/15 clamps never bind for
            // x,y in [0,13]. Packed test: rr = xy - ((ax-5)*256 + (ay-5));
            // in-window  <=>  low byte < 10  AND  (rr>>8) < 10 (unsigned).
            // y<by borrows 1 from the x field, but then the low byte lands in
            // [243,255] and the y test rejects, so no false positives.
            const int ax = flat / L;
            const int ay = flat - ax * L;
            const int q = (ax - 5) * 256 + (ay - 5);
#pragma unroll
            for (int i = 0; i < 16; ++i) {
                const int rr = xy[i] - q;
                const bool in = ((rr & 255) < 10) & (((unsigned)rr >> 8) < 10u);
                key[i] = in ? (key[i] & 255u) : key[i];
            }
        }
    }

    int cx[4], cy[4];
#pragma unroll
    for (int i = 0; i < 4; ++i) {
        cx[i] = peaks[i] / L;
        cy[i] = peaks[i] - cx[i] * L;
    }

    // farthest pair among 6, first-index-wins argmax
    const int pa[6] = {0, 0, 0, 1, 1, 2};
    const int pb[6] = {1, 2, 3, 2, 3, 3};
    int bestd = -1, ax0 = 0, ay0 = 0, ax1 = 0, ay1 = 0;
#pragma unroll
    for (int p = 0; p < 6; ++p) {
        const int dx = cx[pb[p]] - cx[pa[p]];
        const int dy = cy[pb[p]] - cy[pa[p]];
        const int d = dx * dx + dy * dy;
        if (d > bestd) { bestd = d; ax0 = cx[pa[p]]; ay0 = cy[pa[p]];
                         ax1 = cx[pb[p]]; ay1 = cy[pb[p]]; }
    }

    // d1 < d2  <=>  2(ax1-ax0)x + 2(ay1-ay0)y < (ax1-ax0)(ax0+ax1)+(ay1-ay0)(ay0+ay1)
    const int Ax = (ax1 - ax0) * 2, Ay = (ay1 - ay0) * 2;
    const int K = (ax1 - ax0) * (ax0 + ax1) + (ay1 - ay0) * (ay0 + ay1);

    v4f* __restrict__ o1 = out4 + (size_t)b * NV4;
    v4f* __restrict__ o2 = out4 + (size_t)(B + b) * NV4;
#pragma unroll
    for (int g = 0; g < 4; ++g) {
        v4f mv, nv;
#pragma unroll
        for (int j = 0; j < 4; ++j) {
            const int i = (g << 2) + j;
            const int x = xy[i] >> 8, y = xy[i] & 255;
            const bool t = (Ax * x + Ay * y) < K;
            mv[j] = t ? 1.0f : 0.0f;
            nv[j] = t ? 0.0f : 1.0f;
        }
        if (g < 3) {
            __builtin_nontemporal_store(mv, o1 + (g << 4) + s);
            __builtin_nontemporal_store(nv, o2 + (g << 4) + s);
        } else if (s == 0) {
            __builtin_nontemporal_store(mv, o1 + 48);
            __builtin_nontemporal_store(nv, o2 + 48);
        }
    }
}

extern "C" void kernel_launch(void* const* d_in, const int* in_sizes, int n_in,
                              void* d_out, int out_size, void* d_ws, size_t ws_size,
                              hipStream_t stream) {
    const v4f* hm4 = (const v4f*)d_in[0];
    v4f* out4 = (v4f*)d_out;
    const int B = in_sizes[0] / NPIX;        // 131072
    const int blocks = (B + 15) / 16;        // 16 batches per 256-thread block
    nms_kernel<<<blocks, 256, 0, stream>>>(hm4, out4, B);
}

// Round 2
// 278.890 us; speedup vs baseline: 1.0751x; 1.0751x over previous
//
#include <hip/hip_runtime.h>

// NMS + farthest-pair + Voronoi masks, B=131072 heatmaps of 14x14 fp32.
// 4 batches per 64-lane wave (16 lanes = 1 DPP row per batch).
// Argmax = single u32-key max reduction (value<<8 | 255-flat): value-max and
// first-occurrence index in ONE tree+4-step-DPP reduction, pure VALU, no LDS.
// Survivors of (v > 0.6) lie in (0.6,1) -> fp32 exponent fixed at 126, so the
// 23-bit mantissa (+1) preserves exact float ordering in integer compare.
//
// r2: revert nontemporal hints (r1 regression: input is L3-resident across
// timed iterations; nt loads forced the 103MB read stream to HBM every
// iteration). Keep the r1 VGPR diet (key[16]+packed xy[16] only), the
// v_max3_u32 reduction tree, and the packed-byte window test.

typedef float v4f __attribute__((ext_vector_type(4)));

constexpr int L = 14;
constexpr int NPIX = L * L;   // 196
constexpr int NV4 = NPIX / 4; // 49

template <int CTRL>
__device__ __forceinline__ unsigned dpp_maxu(unsigned x) {
    unsigned y = (unsigned)__builtin_amdgcn_update_dpp(0, (int)x, CTRL, 0xF, 0xF, true);
    return x > y ? x : y;
}
__device__ __forceinline__ unsigned row_max16u(unsigned x) {
    x = dpp_maxu<0xB1>(x);   // quad_perm xor1
    x = dpp_maxu<0x4E>(x);   // quad_perm xor2
    x = dpp_maxu<0x141>(x);  // row_half_mirror
    x = dpp_maxu<0x140>(x);  // row_mirror
    return x;
}
__device__ __forceinline__ unsigned umax2(unsigned a, unsigned b) { return a > b ? a : b; }
__device__ __forceinline__ unsigned umax3(unsigned a, unsigned b, unsigned c) {
    return umax2(umax2(a, b), c);  // -> v_max3_u32
}

__global__ __launch_bounds__(256) void nms_kernel(const v4f* __restrict__ hm4,
                                                  v4f* __restrict__ out4, int B) {
    const int lane = threadIdx.x & 63;
    const int s = lane & 15;
    const int b = blockIdx.x * 16 + ((threadIdx.x >> 6) << 2) + (lane >> 4);
    if (b >= B) return;

    const v4f* __restrict__ bp = hm4 + (size_t)b * NV4;
    v4f a0 = bp[s];
    v4f a1 = bp[16 + s];
    v4f a2 = bp[32 + s];
    v4f a3 = {0.f, 0.f, 0.f, 0.f};   // sentinel slots = zero heat
    if (s == 0) a3 = bp[48];

    // flat(slot i) = 4s + 64*(i>>2) + (i&3); sentinel flats 196..255 have
    // inv < 60 so they lose to every real zero-slot (inv >= 60). Low byte of
    // key is ALWAYS inv, so "suppress" == key &= 255.
    unsigned key[16];
    int xy[16];                       // (x<<8)|y, x in [0,18], y in [0,13]
    const int s4 = s << 2;
#pragma unroll
    for (int i = 0; i < 16; ++i) {
        const int fl = s4 + ((i >> 2) << 6) + (i & 3);
        const int x = fl / L, y = fl - (fl / L) * L;
        xy[i] = (x << 8) | y;
        const float v = (i < 4) ? a0[i] : (i < 8) ? a1[i - 4] : (i < 12) ? a2[i - 8] : a3[i - 12];
        const unsigned inv = 255u - (unsigned)fl;
        const unsigned kpos = (((__float_as_uint(v) & 0x7FFFFFu) + 1u) << 8) | inv;
        key[i] = (v > 0.6f) ? kpos : inv;
    }

    int peaks[4];
#pragma unroll
    for (int r = 0; r < 4; ++r) {
        // balanced tree: 5x max3 over 15 + fold with key[15] (8 VALU total)
        const unsigned t0 = umax3(key[0], key[1], key[2]);
        const unsigned t1 = umax3(key[3], key[4], key[5]);
        const unsigned t2 = umax3(key[6], key[7], key[8]);
        const unsigned t3 = umax3(key[9], key[10], key[11]);
        const unsigned t4 = umax3(key[12], key[13], key[14]);
        unsigned mk = umax2(umax3(t0, t1, t2), umax3(t3, t4, key[15]));
        mk = row_max16u(mk);
        const int flat = 255 - (int)(mk & 255u);
        peaks[r] = flat;
        if (r < 3) {
            // window [ax-5, ax+5) x [ay-5, ay+5); 0/15 clamps never bind for
            // x,y in [0,13]. Packed test: rr = xy - ((ax-5)*256 + (ay-5));
            // in-window  <=>  low byte < 10  AND  (rr>>8) < 10 (unsigned).
            // y<by borrows 1 from the x field, but then the low byte lands in
            // [243,255] and the y test rejects, so no false positives.
            const int ax = flat / L;
            const int ay = flat - ax * L;
            const int q = (ax - 5) * 256 + (ay - 5);
#pragma unroll
            for (int i = 0; i < 16; ++i) {
                const int rr = xy[i] - q;
                const bool in = ((rr & 255) < 10) & (((unsigned)rr >> 8) < 10u);
                key[i] = in ? (key[i] & 255u) : key[i];
            }
        }
    }

    int cx[4], cy[4];
#pragma unroll
    for (int i = 0; i < 4; ++i) {
        cx[i] = peaks[i] / L;
        cy[i] = peaks[i] - cx[i] * L;
    }

    // farthest pair among 6, first-index-wins argmax
    const int pa[6] = {0, 0, 0, 1, 1, 2};
    const int pb[6] = {1, 2, 3, 2, 3, 3};
    int bestd = -1, ax0 = 0, ay0 = 0, ax1 = 0, ay1 = 0;
#pragma unroll
    for (int p = 0; p < 6; ++p) {
        const int dx = cx[pb[p]] - cx[pa[p]];
        const int dy = cy[pb[p]] - cy[pa[p]];
        const int d = dx * dx + dy * dy;
        if (d > bestd) { bestd = d; ax0 = cx[pa[p]]; ay0 = cy[pa[p]];
                         ax1 = cx[pb[p]]; ay1 = cy[pb[p]]; }
    }

    // d1 < d2  <=>  2(ax1-ax0)x + 2(ay1-ay0)y < (ax1-ax0)(ax0+ax1)+(ay1-ay0)(ay0+ay1)
    const int Ax = (ax1 - ax0) * 2, Ay = (ay1 - ay0) * 2;
    const int K = (ax1 - ax0) * (ax0 + ax1) + (ay1 - ay0) * (ay0 + ay1);

    v4f* __restrict__ o1 = out4 + (size_t)b * NV4;
    v4f* __restrict__ o2 = out4 + (size_t)(B + b) * NV4;
#pragma unroll
    for (int g = 0; g < 4; ++g) {
        v4f mv, nv;
#pragma unroll
        for (int j = 0; j < 4; ++j) {
            const int i = (g << 2) + j;
            const int x = xy[i] >> 8, y = xy[i] & 255;
            const bool t = (Ax * x + Ay * y) < K;
            mv[j] = t ? 1.0f : 0.0f;
            nv[j] = t ? 0.0f : 1.0f;
        }
        if (g < 3) {
            o1[(g << 4) + s] = mv;
            o2[(g << 4) + s] = nv;
        } else if (s == 0) {
            o1[48] = mv;
            o2[48] = nv;
        }
    }
}

extern "C" void kernel_launch(void* const* d_in, const int* in_sizes, int n_in,
                              void* d_out, int out_size, void* d_ws, size_t ws_size,
                              hipStream_t stream) {
    const v4f* hm4 = (const v4f*)d_in[0];
    v4f* out4 = (v4f*)d_out;
    const int B = in_sizes[0] / NPIX;        // 131072
    const int blocks = (B + 15) / 16;        // 16 batches per 256-thread block
    nms_kernel<<<blocks, 256, 0, stream>>>(hm4, out4, B);
}